// Round 3
// baseline (233.217 us; speedup 1.0000x reference)
//
#include <hip/hip_runtime.h>
#include <cstdint>

typedef __bf16 bf16;
typedef __bf16 bf16x4 __attribute__((ext_vector_type(4)));
typedef __bf16 bf16x8 __attribute__((ext_vector_type(8)));
typedef float floatx4 __attribute__((ext_vector_type(4)));
typedef float f32x16 __attribute__((ext_vector_type(16)));
typedef unsigned int uint2v __attribute__((ext_vector_type(2)));
typedef unsigned int uint4v __attribute__((ext_vector_type(4)));

typedef const __attribute__((address_space(1))) void* as1_cvptr;
typedef __attribute__((address_space(3))) void* as3_vptr;

__device__ __forceinline__ void gl_lds16(const void* g, void* l) {
  __builtin_amdgcn_global_load_lds((as1_cvptr)(uintptr_t)g,
                                   (as3_vptr)(uint32_t)(uintptr_t)l, 16, 0, 0);
}

#define EMBED 1024
#define SEQ 2048
#define NH 16
#define DH 64
// softmax scale folded into Q at projection time: 0.125 * log2(e)
#define QSCALE 0.18033688f

// pack two f32 -> one u32 of 2 bf16 (compiler fuses to v_cvt_pk_bf16_f32)
__device__ __forceinline__ unsigned pk_bf16(float a, float b) {
  unsigned short ua = __builtin_bit_cast(unsigned short, (bf16)a);
  unsigned short ub = __builtin_bit_cast(unsigned short, (bf16)b);
  return (unsigned)ua | ((unsigned)ub << 16);
}

// ---------------------------------------------------------------------------
// Kernel A: prep — grid (256,4). z<3: transpose+downcast W z; z=3: x->bf16.
// ---------------------------------------------------------------------------
__global__ __launch_bounds__(256) void prep(
    const float* __restrict__ x, const float* __restrict__ Wq,
    const float* __restrict__ Wk, const float* __restrict__ Wv,
    bf16* __restrict__ xb, bf16* __restrict__ Wqt,
    bf16* __restrict__ Wkt, bf16* __restrict__ Wvt) {
  __shared__ __align__(16) bf16 tile[64][72];
  int z = blockIdx.y;
  int t = threadIdx.x;
  if (z == 3) {
    size_t base = ((size_t)blockIdx.x * 256 + t) * 8;
#pragma unroll
    for (int it = 0; it < 8; ++it) {
      size_t i = base + (size_t)it * (256 * 256 * 8);
      floatx4 a = *(const floatx4*)(x + i);
      floatx4 bv = *(const floatx4*)(x + i + 4);
      bf16x8 o;
#pragma unroll
      for (int j = 0; j < 4; ++j) { o[j] = (bf16)a[j]; o[4 + j] = (bf16)bv[j]; }
      *(bf16x8*)(xb + i) = o;
    }
    return;
  }
  const float* W = (z == 0) ? Wq : (z == 1) ? Wk : Wv;
  bf16* Wt = (z == 0) ? Wqt : (z == 1) ? Wkt : Wvt;
  int k0 = (blockIdx.x >> 4) * 64, n0 = (blockIdx.x & 15) * 64;
  int r = t >> 3, c = (t & 7) * 8;
#pragma unroll
  for (int half = 0; half < 2; ++half) {
    const float* src = &W[(size_t)(k0 + r + half * 32) * EMBED + n0 + c];
    floatx4 f0 = *(const floatx4*)src;
    floatx4 f1 = *(const floatx4*)(src + 4);
    bf16x8 o;
#pragma unroll
    for (int j = 0; j < 4; ++j) { o[j] = (bf16)f0[j]; o[4 + j] = (bf16)f1[j]; }
    *(bf16x8*)&tile[r + half * 32][c] = o;
  }
  __syncthreads();
#pragma unroll
  for (int p = 0; p < 2; ++p) {
    int nn = (t >> 3) + p * 32, kk = (t & 7) * 8;
    bf16x8 v;
#pragma unroll
    for (int i = 0; i < 8; ++i) v[i] = tile[kk + i][nn];
    *(bf16x8*)&Wt[(size_t)(n0 + nn) * EMBED + k0 + kk] = v;
  }
}

// ---------------------------------------------------------------------------
// Kernel B v2: fused QKV projection. Operand order chosen per z so C rows =
// output's fastest dim -> packed bf16x4 (8B) stores: 16 store instrs/thread
// (was 64 scalar). z<2: A=Wt (m=outdim), B=X (n=seq). z=2: A=X (m=seq),
// B=Wt (n=outdim).
// ---------------------------------------------------------------------------
__global__ __launch_bounds__(256) void qkv3(
    const bf16* __restrict__ Xb, const bf16* __restrict__ Wqt,
    const bf16* __restrict__ Wkt, const bf16* __restrict__ Wvt,
    bf16* __restrict__ qo, bf16* __restrict__ ko, bf16* __restrict__ vto) {
  __shared__ __align__(16) bf16 As[128 * 32];
  __shared__ __align__(16) bf16 Bs[128 * 32];

  int gid = blockIdx.x;
  int z = gid % 3;
  int rem = gid / 3;
  int bxx = rem & 7, byy = rem >> 3;  // bxx: outdim tile (8), byy: seq tile (32)

  const bf16* Wt = (z == 0) ? Wqt : (z == 1) ? Wkt : Wvt;
  bf16* out = (z == 0) ? qo : (z == 1) ? ko : vto;
  int m0 = (z == 2 ? byy : bxx) * 128;
  int n0 = (z == 2 ? bxx : byy) * 128;
  const bf16* Asrc = (z == 2) ? Xb : Wt;
  const bf16* Bsrc = (z == 2) ? Wt : Xb;
  float oscale = (z == 0) ? QSCALE : 1.0f;

  int t = threadIdx.x;
  int w = t >> 6, lane = t & 63, ln = lane & 15, quad = lane >> 4;
  int wm = (w >> 1) * 64, wn = (w & 1) * 64;

  floatx4 acc[4][4];
#pragma unroll
  for (int i = 0; i < 4; ++i)
#pragma unroll
    for (int j = 0; j < 4; ++j) acc[i][j] = floatx4{0.f, 0.f, 0.f, 0.f};

  int sr = t >> 2, sc = (t & 3) * 8;
  const bf16* ag = Asrc + (size_t)(m0 + sr) * EMBED + sc;
  const bf16* bg = Bsrc + (size_t)(n0 + sr) * EMBED + sc;
  bf16* al = As + sr * 32 + sc;
  bf16* bl = Bs + sr * 32 + sc;

  for (int k0 = 0; k0 < EMBED; k0 += 32) {
    __syncthreads();
    gl_lds16(ag + k0, al);
    gl_lds16(ag + k0 + (size_t)64 * EMBED, al + 64 * 32);
    gl_lds16(bg + k0, bl);
    gl_lds16(bg + k0 + (size_t)64 * EMBED, bl + 64 * 32);
    __syncthreads();

    bf16x8 afr[4], bfr[4];
#pragma unroll
    for (int i = 0; i < 4; ++i)
      afr[i] = *(const bf16x8*)&As[(wm + i * 16 + ln) * 32 + quad * 8];
#pragma unroll
    for (int j = 0; j < 4; ++j)
      bfr[j] = *(const bf16x8*)&Bs[(wn + j * 16 + ln) * 32 + quad * 8];
#pragma unroll
    for (int i = 0; i < 4; ++i)
#pragma unroll
      for (int j = 0; j < 4; ++j)
        acc[i][j] =
            __builtin_amdgcn_mfma_f32_16x16x32_bf16(afr[i], bfr[j], acc[i][j], 0, 0, 0);
  }

  // Epilogue: C/D 16x16 layout col=lane&15, row=quad*4+r (rows consecutive)
  if (z != 2) {
    // m=outdim (h,d): 4 consecutive d per reg quad -> 8B store at [b,h,ns,d]
#pragma unroll
    for (int i = 0; i < 4; ++i) {
      int od = m0 + wm + i * 16 + quad * 4;  // aligned 4, no h-crossing
      int hq = od >> 6, d0 = od & 63;
#pragma unroll
      for (int j = 0; j < 4; ++j) {
        int c = n0 + wn + j * 16 + ln;  // global seq 0..4095
        int bb = c >> 11, ns = c & 2047;
        bf16x4 pv;
#pragma unroll
        for (int r = 0; r < 4; ++r) pv[r] = (bf16)(acc[i][j][r] * oscale);
        *(bf16x4*)&out[(((size_t)(bb * NH + hq)) * SEQ + ns) * DH + d0] = pv;
      }
    }
  } else {
    // m=seq: 4 consecutive ns per reg quad -> 8B store at [b*16+h][d][ns]
#pragma unroll
    for (int i = 0; i < 4; ++i) {
      int sq = m0 + wm + i * 16 + quad * 4;  // aligned 4, no b-crossing
      int bb = sq >> 11, ns0 = sq & 2047;
#pragma unroll
      for (int j = 0; j < 4; ++j) {
        int od = n0 + wn + j * 16 + ln;
        int hq = od >> 6, d = od & 63;
        bf16x4 pv;
#pragma unroll
        for (int r = 0; r < 4; ++r) pv[r] = (bf16)acc[i][j][r];
        *(bf16x4*)&out[(((size_t)(bb * NH + hq)) * DH + d) * SEQ + ns0] = pv;
      }
    }
  }
}

// ---------------------------------------------------------------------------
// Kernel C: flash v6 — occupancy + VALU-economy rework of v5.
// 512 thr / 8 waves = 4 qg x 2 splits (1024 keys each, 16x 64-key tiles).
// Single-buffered K/V LDS (32KB, XOR-swizzled chunks) staged via
// global_load_lds with inverse-swizzled global source (rule #21).
// All 16 ds_read_b128/iter use 4 precomputed xaddr regs + compile-time
// immediates (zero per-iter address VALU). In-reg P via permlane32_swap.
// LDS 36KB, VGPR<=85 (launch_bounds 512,6) -> 3 blocks/CU = 6 waves/SIMD.
// Swizzle: element (row, chunk16B c) stored at row*128 + ((c ^ (row&7))<<4).
// ---------------------------------------------------------------------------
__global__ __launch_bounds__(512, 6) void flash(
    const bf16* __restrict__ Qg, const bf16* __restrict__ Kg,
    const bf16* __restrict__ Vtg, float* __restrict__ Og) {
  // K: [2 split][64 key][128B] at 0..16384; V: [2 split][64 d][128B] at 16384..32768
  // merge overlay: Om [128 q][68]f at 0; Lm [2][128]f at 34816.
  __shared__ __align__(16) char smem[36864];
  char* sm = smem;
  float* Om = (float*)smem;
  float* Lm = (float*)(smem + 34816);

  int t = threadIdx.x;
  int lane = t & 63, w = t >> 6;
  int col = lane & 31, hi = lane >> 5;
  int qg = w >> 1, split = w & 1;
  int bh = blockIdx.y;
  int b = bh >> 4, h = bh & 15;
  const bf16* Q = Qg + (size_t)bh * SEQ * DH;
  const bf16* K = Kg + (size_t)bh * SEQ * DH;
  const bf16* Vt = Vtg + (size_t)bh * DH * SEQ;
  int q0 = blockIdx.x * 128 + qg * 32;

  // Q as B-operand (carries QSCALE): lane holds q=col, k-elems kc*16+hi*8+j
  bf16x8 bq[4];
#pragma unroll
  for (int kc = 0; kc < 4; ++kc)
    bq[kc] = *(const bf16x8*)&Q[(size_t)(q0 + col) * DH + kc * 16 + hi * 8];

  f32x16 oacc[2];
#pragma unroll
  for (int m = 0; m < 2; ++m)
#pragma unroll
    for (int r = 0; r < 16; ++r) oacc[m][r] = 0.f;
  float li = 0.f;

  // LDS read addresses: xaddr[k2] serves K reads (k2=kc; +mt*4096) and
  // V reads (k2=c; +16384+dhalf*4096). Swizzled chunk = (k2*2+hi)^(row&7),
  // row&7 == col&7 for both K (row=mt*32+col) and V (row=dhalf*32+col).
  int xaddr[4];
#pragma unroll
  for (int k2 = 0; k2 < 4; ++k2)
    xaddr[k2] = split * 8192 + col * 128 + ((((col & 7) ^ (k2 * 2 + hi))) << 4);

  // staging roles: wave w -> (rs=split, ra=K/V, rh=half of 8KB tile)
  int rs = w >> 2, ra = (w >> 1) & 1, rh = w & 1;
  int row0 = lane >> 3;
  int cswz = (lane & 7) ^ (row0 & 7);
  const char* gsrc;
  int ldsb, itstride, istride;
  if (ra == 0) {
    // K rows (keys): row = rh*32 + i*8 + row0; src row stride 128B
    gsrc = (const char*)K + ((size_t)rs * 1024 + rh * 32 + row0) * 128 + cswz * 16;
    ldsb = rs * 8192 + rh * 4096;
    itstride = 8192;   // 64 keys * 128B per iteration
    istride = 1024;    // 8 rows per gl_lds
  } else {
    // V rows (d): row = rh*32 + i*8 + row0; src row stride SEQ*2=4096B
    gsrc = (const char*)Vt + ((size_t)(rh * 32 + row0)) * 4096 + rs * 2048 + cswz * 16;
    ldsb = 16384 + rs * 8192 + rh * 4096;
    itstride = 128;    // 64 keys * 2B per iteration
    istride = 32768;   // 8 rows per gl_lds
  }

#pragma unroll 1
  for (int it = 0; it < 16; ++it) {
    __syncthreads();  // previous compute done before overwrite
    {
      const char* gs = gsrc + (size_t)it * itstride;
      char* ld = sm + ldsb + lane * 16;
      gl_lds16(gs, ld);
      gl_lds16(gs + istride, ld + 1024);
      gl_lds16(gs + 2 * istride, ld + 2048);
      gl_lds16(gs + 3 * istride, ld + 3072);
    }
    __syncthreads();  // staged data visible

#pragma unroll
    for (int mt = 0; mt < 2; ++mt) {
      // S^T = K.Q^T: D[m=key][n=q]; lane: q=col, key=mt*32+(r&3)+8(r>>2)+4hi
      f32x16 s;
#pragma unroll
      for (int r = 0; r < 16; ++r) s[r] = 0.f;
#pragma unroll
      for (int kc = 0; kc < 4; ++kc) {
        bf16x8 ak = *(const bf16x8*)(sm + xaddr[kc] + mt * 4096);
        s = __builtin_amdgcn_mfma_f32_32x32x16_bf16(ak, bq[kc], s, 0, 0, 0);
      }
#pragma unroll
      for (int cc = 0; cc < 2; ++cc) {
        int rb = cc * 8;
        float e0 = exp2f(s[rb + 0]), e1 = exp2f(s[rb + 1]);
        float e2 = exp2f(s[rb + 2]), e3 = exp2f(s[rb + 3]);
        float e4 = exp2f(s[rb + 4]), e5 = exp2f(s[rb + 5]);
        float e6 = exp2f(s[rb + 6]), e7 = exp2f(s[rb + 7]);
        li += ((e0 + e1) + (e2 + e3)) + ((e4 + e5) + (e6 + e7));
        // T12: pack + permlane32_swap -> PV B-operand in registers
        unsigned lo0 = pk_bf16(e0, e1), lo1 = pk_bf16(e2, e3);
        unsigned h0 = pk_bf16(e4, e5), h1 = pk_bf16(e6, e7);
        uint2v r02 = __builtin_amdgcn_permlane32_swap(lo0, h0, false, false);
        uint2v r13 = __builtin_amdgcn_permlane32_swap(lo1, h1, false, false);
        uint4v uu;
        uu[0] = r02[0]; uu[1] = r13[0]; uu[2] = r02[1]; uu[3] = r13[1];
        bf16x8 pb = __builtin_bit_cast(bf16x8, uu);  // B[k=key][n=q]

        int c = mt * 2 + cc;  // 16-key chunk in tile; V chunk idx = c*2+hi
        bf16x8 av0 = *(const bf16x8*)(sm + xaddr[c] + 16384);
        bf16x8 av1 = *(const bf16x8*)(sm + xaddr[c] + 16384 + 4096);
        oacc[0] = __builtin_amdgcn_mfma_f32_32x32x16_bf16(av0, pb, oacc[0], 0, 0, 0);
        oacc[1] = __builtin_amdgcn_mfma_f32_32x32x16_bf16(av1, pb, oacc[1], 0, 0, 0);
      }
    }
  }

  // ---- 2-way split-K merge (exact): O = O0+O1, l = l0+l1 ----
  li += __shfl_xor(li, 32, 64);
  __syncthreads();  // all K/V LDS reads done before overlay writes
  if (lane < 32) Lm[split * 128 + qg * 32 + col] = li;
  if (split == 1) {
#pragma unroll
    for (int m = 0; m < 2; ++m)
#pragma unroll
      for (int rr = 0; rr < 4; ++rr) {
        floatx4 v4;
#pragma unroll
        for (int j = 0; j < 4; ++j) v4[j] = oacc[m][rr * 4 + j];
        *(floatx4*)&Om[(qg * 32 + col) * 68 + m * 32 + rr * 8 + hi * 4] = v4;
      }
  }
  __syncthreads();
  if (split == 0) {
#pragma unroll
    for (int m = 0; m < 2; ++m)
#pragma unroll
      for (int rr = 0; rr < 4; ++rr) {
        floatx4 v4 =
            *(const floatx4*)&Om[(qg * 32 + col) * 68 + m * 32 + rr * 8 + hi * 4];
#pragma unroll
        for (int j = 0; j < 4; ++j) v4[j] += oacc[m][rr * 4 + j];
        *(floatx4*)&Om[(qg * 32 + col) * 68 + m * 32 + rr * 8 + hi * 4] = v4;
      }
  }
  __syncthreads();

  // coalesced readout: 128 q x 64 d, scale by 1/l, f32x4 stores
#pragma unroll
  for (int rep = 0; rep < 4; ++rep) {
    int idx = rep * 512 + t;
    int q = idx >> 4, dc = (idx & 15) * 4;
    float lt = Lm[q] + Lm[128 + q];
    float inv = 1.0f / lt;
    floatx4 ov = *(const floatx4*)&Om[q * 68 + dc];
    ov[0] *= inv; ov[1] *= inv; ov[2] *= inv; ov[3] *= inv;
    int ns = blockIdx.x * 128 + q;
    *(floatx4*)&Og[((size_t)(b * SEQ + ns)) * EMBED + h * DH + dc] = ov;
  }
}

// ---------------------------------------------------------------------------
// ws (38 MB): q [0,4M) k [4M,8M) vt [8M,12M) wqt..wvt [12M,15M) xb [15M,19M)
// ---------------------------------------------------------------------------
extern "C" void kernel_launch(void* const* d_in, const int* in_sizes, int n_in,
                              void* d_out, int out_size, void* d_ws, size_t ws_size,
                              hipStream_t stream) {
  const int XEL = 2 * 2048 * 1024;
  const float *x, *Wq, *Wk, *Wv;
  if (in_sizes[0] == XEL) {
    x = (const float*)d_in[0];
    Wq = (const float*)d_in[1];
    Wk = (const float*)d_in[2];
    Wv = (const float*)d_in[3];
  } else {
    Wk = (const float*)d_in[0];
    Wq = (const float*)d_in[1];
    Wv = (const float*)d_in[2];
    x = (const float*)d_in[3];
  }
  bf16* ws = (bf16*)d_ws;

  const size_t M1 = 1024 * 1024;
  bf16* q_ws = ws;
  bf16* k_ws = ws + 4 * M1;
  bf16* vt_ws = ws + 8 * M1;
  bf16* wqt = ws + 12 * M1;
  bf16* wkt = ws + 13 * M1;
  bf16* wvt = ws + 14 * M1;
  bf16* xb = ws + 15 * M1;

  prep<<<dim3(256, 4), 256, 0, stream>>>(x, Wq, Wk, Wv, xb, wqt, wkt, wvt);
  qkv3<<<dim3(768), 256, 0, stream>>>(xb, wqt, wkt, wvt, q_ws, k_ws, vt_ws);
  flash<<<dim3(16, 32), 512, 0, stream>>>(q_ws, k_ws, vt_ws, (float*)d_out);
}